// Round 1
// baseline (43.846 us; speedup 1.0000x reference)
//
#include <hip/hip_runtime.h>
#include <math.h>

#define BD 256
#define NPATCH 196   // 14*14
#define NPIX 784     // 28*28
#define NFEAT 784    // NPATCH*4
#define NOUT 10

__device__ __forceinline__ void cmul(float& xr, float& xi, float yr, float yi) {
    float r = xr * yr - xi * yi;
    float i = xr * yi + xi * yr;
    xr = r; xi = i;
}

__global__ __launch_bounds__(BD) void quanv_fused_kernel(
    const int* __restrict__ x,      // (B,1,28,28)
    const float* __restrict__ params, // (4,2)
    const float* __restrict__ fc_w,   // (10,784)
    const float* __restrict__ fc_b,   // (10,)
    float* __restrict__ out)          // (B,10)
{
    __shared__ int   img[NPIX];
    __shared__ float feat[NFEAT];
    __shared__ float part[4 * NOUT];

    const int b = blockIdx.x;
    const int t = threadIdx.x;

    // ---- stage image into LDS (coalesced int4) ----
    if (t < NPATCH) {
        const int4* src = (const int4*)(x + (size_t)b * NPIX);
        int4 v = src[t];
        img[t * 4 + 0] = v.x;
        img[t * 4 + 1] = v.y;
        img[t * 4 + 2] = v.z;
        img[t * 4 + 3] = v.w;
    }

    // ---- per-layer RZ phase factors e_{l,w} = exp(+i*phi/2) (conj for bit==0) ----
    float ewr[2][4], ewi[2][4];
#pragma unroll
    for (int l = 0; l < 2; ++l) {
#pragma unroll
        for (int w = 0; w < 4; ++w) {
            float phi = params[w * 2 + l];   // params[w, l], NL=2
            float s, c;
            sincosf(0.5f * phi, &s, &c);
            ewr[l][w] = c; ewi[l][w] = s;
        }
    }

    __syncthreads();

    // ---- simulate one 2x2 patch per thread ----
    if (t < NPATCH) {
        const int i = t / 14;
        const int j = t - i * 14;
        const int base = (2 * i) * 28 + 2 * j;
        const float k = 3.14159265358979323846f / 510.0f;  // pi/255 * 0.5
        float th0 = img[base]      * k;   // half-angles
        float th1 = img[base + 1]  * k;
        float th2 = img[base + 28] * k;
        float th3 = img[base + 29] * k;

        float cw[4], sw[4];
        sincosf(th0, &sw[0], &cw[0]);
        sincosf(th1, &sw[1], &cw[1]);
        sincosf(th2, &sw[2], &cw[2]);
        sincosf(th3, &sw[3], &cw[3]);

        // product state; idx bit layout: q0 = bit3 (MSB) ... q3 = bit0
        float ar[16], ai[16];
#pragma unroll
        for (int idx = 0; idx < 16; ++idx) {
            float p = (((idx >> 3) & 1) ? sw[0] : cw[0])
                    * (((idx >> 2) & 1) ? sw[1] : cw[1])
                    * (((idx >> 1) & 1) ? sw[2] : cw[2])
                    * (((idx     ) & 1) ? sw[3] : cw[3]);
            ar[idx] = p; ai[idx] = 0.0f;
        }

#pragma unroll
        for (int l = 0; l < 2; ++l) {
            // pair products: A over (q0,q1), B over (q2,q3)
            float Ar[4], Ai[4], Br[4], Bi[4];
#pragma unroll
            for (int kk = 0; kk < 4; ++kk) {
                float e0i = ((kk >> 1) & 1) ? ewi[l][0] : -ewi[l][0];
                float e1i = ((kk     ) & 1) ? ewi[l][1] : -ewi[l][1];
                Ar[kk] = ewr[l][0] * ewr[l][1] - e0i * e1i;
                Ai[kk] = ewr[l][0] * e1i + e0i * ewr[l][1];
                float e2i = ((kk >> 1) & 1) ? ewi[l][2] : -ewi[l][2];
                float e3i = ((kk     ) & 1) ? ewi[l][3] : -ewi[l][3];
                Br[kk] = ewr[l][2] * ewr[l][3] - e2i * e3i;
                Bi[kk] = ewr[l][2] * e3i + e2i * ewr[l][3];
            }
            // apply diagonal phase
#pragma unroll
            for (int idx = 0; idx < 16; ++idx) {
                float pr = Ar[idx >> 2], pi = Ai[idx >> 2];
                cmul(pr, pi, Br[idx & 3], Bi[idx & 3]);
                cmul(ar[idx], ai[idx], pr, pi);
            }
            // CNOT chain: control w -> target w+1  (w=0,1,2)
#pragma unroll
            for (int w = 0; w < 3; ++w) {
                const int cs = 3 - w, ts = 2 - w;
#pragma unroll
                for (int i2 = 0; i2 < 16; ++i2) {
                    if ((((i2 >> cs) & 1) == 1) && (((i2 >> ts) & 1) == 0)) {
                        int j2 = i2 | (1 << ts);
                        float tr = ar[i2]; ar[i2] = ar[j2]; ar[j2] = tr;
                        float ti = ai[i2]; ai[i2] = ai[j2]; ai[j2] = ti;
                    }
                }
            }
        }

        // measure Z on each qubit
        float z0 = 0.f, z1 = 0.f, z2 = 0.f, z3 = 0.f;
#pragma unroll
        for (int idx = 0; idx < 16; ++idx) {
            float p = ar[idx] * ar[idx] + ai[idx] * ai[idx];
            z0 += ((idx >> 3) & 1) ? -p : p;
            z1 += ((idx >> 2) & 1) ? -p : p;
            z2 += ((idx >> 1) & 1) ? -p : p;
            z3 += ((idx     ) & 1) ? -p : p;
        }
        feat[t * 4 + 0] = z0;
        feat[t * 4 + 1] = z1;
        feat[t * 4 + 2] = z2;
        feat[t * 4 + 3] = z3;
    }

    __syncthreads();

    // ---- FC: logits[o] = feat . fc_w[o] + fc_b[o] ----
    float acc[NOUT];
#pragma unroll
    for (int o = 0; o < NOUT; ++o) acc[o] = 0.0f;

    for (int f = t; f < NFEAT; f += BD) {
        float fv = feat[f];
#pragma unroll
        for (int o = 0; o < NOUT; ++o) acc[o] += fv * fc_w[o * NFEAT + f];
    }

    // 64-lane wave reduce
#pragma unroll
    for (int o = 0; o < NOUT; ++o) {
#pragma unroll
        for (int off = 32; off > 0; off >>= 1)
            acc[o] += __shfl_xor(acc[o], off, 64);
    }
    const int wv = t >> 6, lane = t & 63;
    if (lane == 0) {
#pragma unroll
        for (int o = 0; o < NOUT; ++o) part[wv * NOUT + o] = acc[o];
    }
    __syncthreads();

    if (t == 0) {
        float lg[NOUT];
        float m = -1e30f;
#pragma unroll
        for (int o = 0; o < NOUT; ++o) {
            lg[o] = part[o] + part[NOUT + o] + part[2 * NOUT + o] + part[3 * NOUT + o] + fc_b[o];
            m = fmaxf(m, lg[o]);
        }
        float sum = 0.0f;
#pragma unroll
        for (int o = 0; o < NOUT; ++o) sum += expf(lg[o] - m);
        float lse = m + logf(sum);
        float* ob = out + (size_t)b * NOUT;
#pragma unroll
        for (int o = 0; o < NOUT; ++o) ob[o] = lg[o] - lse;
    }
}

extern "C" void kernel_launch(void* const* d_in, const int* in_sizes, int n_in,
                              void* d_out, int out_size, void* d_ws, size_t ws_size,
                              hipStream_t stream) {
    const int*   x      = (const int*)d_in[0];
    const float* params = (const float*)d_in[1];
    const float* fc_w   = (const float*)d_in[2];
    const float* fc_b   = (const float*)d_in[3];
    float* out = (float*)d_out;
    const int B = in_sizes[0] / NPIX;  // 4096
    quanv_fused_kernel<<<B, BD, 0, stream>>>(x, params, fc_w, fc_b, out);
}

// Round 2
// 15.374 us; speedup vs baseline: 2.8520x; 2.8520x over previous
//
#include <hip/hip_runtime.h>
#include <math.h>

#define BD 256
#define IPB 4        // images per block, 1 per wave
#define NPIX 784     // 28*28
#define NOUT 10

__global__ __launch_bounds__(BD) void quanv_analytic_kernel(
    const int* __restrict__ x,        // (B,1,28,28) int32, values 0..255
    const float* __restrict__ fc_w,   // (10,784)
    const float* __restrict__ fc_b,   // (10,)
    float* __restrict__ out,          // (B,10)
    int B)
{
    __shared__ int   img[IPB * NPIX];   // 12.25 KB
    __shared__ float lut[256];          // cos(pi*v/255)

    const int t  = threadIdx.x;
    const int b0 = blockIdx.x * IPB;

    // cos LUT for the 256 possible pixel values
    lut[t] = cosf((float)t * (3.14159265358979323846f / 255.0f));

    // stage IPB contiguous images into LDS (coalesced int4)
    {
        const int4* src = (const int4*)(x + (size_t)b0 * NPIX);
        int4* dst = (int4*)img;
        const int nvec = IPB * NPIX / 4;   // 784
        for (int k = t; k < nvec; k += BD) {
            if (b0 * NPIX / 4 + k < (B * NPIX) / 4) dst[k] = src[k];
        }
    }
    __syncthreads();

    const int wv   = t >> 6;
    const int lane = t & 63;
    const int b    = b0 + wv;
    if (b >= B) return;
    const int* im = img + wv * NPIX;

    // FC accumulate: feature f computed analytically on the fly.
    // feature layout: f = patch*4 + comp; patch = i*14+j over 14x14 patches;
    // pixel base = 56*i + 2*j (+1 for comp&1); comp&2 multiplies the row+28 cos.
    float acc[NOUT];
#pragma unroll
    for (int o = 0; o < NOUT; ++o) acc[o] = 0.0f;

    for (int f = lane; f < NPIX; f += 64) {
        const int p = f >> 2, c = f & 3;
        const int i = p / 14, j = p - i * 14;
        const int base = i * 56 + j * 2 + (c & 1);
        float fv = lut[im[base]];
        fv *= (c & 2) ? lut[im[base + 28]] : 1.0f;
#pragma unroll
        for (int o = 0; o < NOUT; ++o) acc[o] += fv * fc_w[o * NPIX + f];
    }

    // wave-level reduce (64 lanes)
#pragma unroll
    for (int o = 0; o < NOUT; ++o) {
#pragma unroll
        for (int off = 32; off > 0; off >>= 1)
            acc[o] += __shfl_xor(acc[o], off, 64);
    }

    if (lane == 0) {
        float lg[NOUT];
        float m = -1e30f;
#pragma unroll
        for (int o = 0; o < NOUT; ++o) {
            lg[o] = acc[o] + fc_b[o];
            m = fmaxf(m, lg[o]);
        }
        float sum = 0.0f;
#pragma unroll
        for (int o = 0; o < NOUT; ++o) sum += expf(lg[o] - m);
        const float lse = m + logf(sum);
        float* ob = out + (size_t)b * NOUT;
#pragma unroll
        for (int o = 0; o < NOUT; ++o) ob[o] = lg[o] - lse;
    }
}

extern "C" void kernel_launch(void* const* d_in, const int* in_sizes, int n_in,
                              void* d_out, int out_size, void* d_ws, size_t ws_size,
                              hipStream_t stream) {
    const int*   x      = (const int*)d_in[0];
    // d_in[1] = params — provably does not affect the output (unit-modulus
    // diagonal phases + basis permutations leave |amplitude|^2 invariant).
    const float* fc_w   = (const float*)d_in[2];
    const float* fc_b   = (const float*)d_in[3];
    float* out = (float*)d_out;
    const int B = in_sizes[0] / NPIX;  // 4096
    const int grid = (B + IPB - 1) / IPB;
    quanv_analytic_kernel<<<grid, BD, 0, stream>>>(x, fc_w, fc_b, out, B);
}

// Round 3
// 14.495 us; speedup vs baseline: 3.0250x; 1.0606x over previous
//
#include <hip/hip_runtime.h>
#include <math.h>

#define BD 128       // 2 waves per block, 1 image per wave
#define IPB 2
#define NPIX 784     // 28*28
#define NOUT 10

__device__ __forceinline__ float cospix(int v) {
    // cos(pi * v / 255) ; v_cos_f32 input is in revolutions: cos(2*pi*r)
    return __builtin_amdgcn_cosf((float)v * (1.0f / 510.0f));
}

__global__ __launch_bounds__(BD) void quanv_analytic2_kernel(
    const int* __restrict__ x,        // (B,1,28,28) int32, 0..255
    const float* __restrict__ fc_w,   // (10,784)
    const float* __restrict__ fc_b,   // (10,)
    float* __restrict__ out,          // (B,10)
    int B)
{
    const int t    = threadIdx.x;
    const int wv   = t >> 6;
    const int lane = t & 63;
    const int b    = blockIdx.x * IPB + wv;
    if (b >= B) return;

    const int* im = x + (size_t)b * NPIX;

    float acc[NOUT];
#pragma unroll
    for (int o = 0; o < NOUT; ++o) acc[o] = 0.0f;

    // 196 patches, patch-major: k=0..2 full, k=3 only lanes 0..3
#pragma unroll
    for (int k = 0; k < 4; ++k) {
        const int p = lane + 64 * k;
        if (p < 196) {
            const int i = p / 14;
            const int j = p - i * 14;
            const int base = i * 56 + j * 2;
            const int2 top = *(const int2*)(im + base);
            const int2 bot = *(const int2*)(im + base + 28);
            const float A = cospix(top.x);
            const float Bv = cospix(top.y);
            const float f2 = A * cospix(bot.x);
            const float f3 = Bv * cospix(bot.y);
#pragma unroll
            for (int o = 0; o < NOUT; ++o) {
                const float4 w = *(const float4*)(fc_w + o * NPIX + 4 * p);
                acc[o] += A * w.x + Bv * w.y + f2 * w.z + f3 * w.w;
            }
        }
    }

    // 64-lane butterfly reduce -> every lane holds the total
#pragma unroll
    for (int o = 0; o < NOUT; ++o) {
#pragma unroll
        for (int off = 32; off > 0; off >>= 1)
            acc[o] += __shfl_xor(acc[o], off, 64);
    }

    if (lane == 0) {
        float lg[NOUT];
        float m = -1e30f;
#pragma unroll
        for (int o = 0; o < NOUT; ++o) {
            lg[o] = acc[o] + fc_b[o];
            m = fmaxf(m, lg[o]);
        }
        float sum = 0.0f;
#pragma unroll
        for (int o = 0; o < NOUT; ++o) sum += expf(lg[o] - m);
        const float lse = m + logf(sum);
        float* ob = out + (size_t)b * NOUT;
#pragma unroll
        for (int o = 0; o < NOUT; ++o) ob[o] = lg[o] - lse;
    }
}

extern "C" void kernel_launch(void* const* d_in, const int* in_sizes, int n_in,
                              void* d_out, int out_size, void* d_ws, size_t ws_size,
                              hipStream_t stream) {
    const int*   x      = (const int*)d_in[0];
    // d_in[1] = params — provably cannot affect the output (unit-modulus
    // diagonal phases + basis-permutation CNOTs leave |amp|^2 invariant).
    const float* fc_w   = (const float*)d_in[2];
    const float* fc_b   = (const float*)d_in[3];
    float* out = (float*)d_out;
    const int B = in_sizes[0] / NPIX;  // 4096
    const int grid = (B + IPB - 1) / IPB;
    quanv_analytic2_kernel<<<grid, BD, 0, stream>>>(x, fc_w, fc_b, out, B);
}

// Round 4
// 13.924 us; speedup vs baseline: 3.1490x; 1.0410x over previous
//
#include <hip/hip_runtime.h>
#include <math.h>

#define BD 256       // 4 waves per block
#define WPB 4
#define IPW 2        // images per wave
#define NPIX 784     // 28*28
#define NOUT 10

__device__ __forceinline__ float cospix(int v) {
    // cos(pi * v / 255); v_cos_f32 input is revolutions
    return __builtin_amdgcn_cosf((float)v * (1.0f / 510.0f));
}

__global__ __launch_bounds__(BD) void quanv_analytic3_kernel(
    const int* __restrict__ x,        // (B,1,28,28) int32, 0..255
    const float* __restrict__ fc_w,   // (10,784)
    const float* __restrict__ fc_b,   // (10,)
    float* __restrict__ out,          // (B,10)
    int B)
{
    const int t    = threadIdx.x;
    const int wv   = t >> 6;
    const int lane = t & 63;
    const int b0   = (blockIdx.x * WPB + wv) * IPW;
    if (b0 >= B) return;

    const int* im0 = x + (size_t)b0 * NPIX;
    const int* im1 = im0 + NPIX;

    float acc0[NOUT], acc1[NOUT];
#pragma unroll
    for (int o = 0; o < NOUT; ++o) { acc0[o] = 0.0f; acc1[o] = 0.0f; }

#pragma unroll
    for (int k = 0; k < 4; ++k) {
        const int p = lane + 64 * k;
        if (p < 196) {
            const int i = p / 14;
            const int j = p - i * 14;
            const int base = i * 56 + j * 2;
            // issue all pixel loads first (ILP), then weights
            const int2 t0 = *(const int2*)(im0 + base);
            const int2 c0 = *(const int2*)(im0 + base + 28);
            const int2 t1 = *(const int2*)(im1 + base);
            const int2 c1 = *(const int2*)(im1 + base + 28);

            const float A0 = cospix(t0.x), B0 = cospix(t0.y);
            const float f20 = A0 * cospix(c0.x), f30 = B0 * cospix(c0.y);
            const float A1 = cospix(t1.x), B1 = cospix(t1.y);
            const float f21 = A1 * cospix(c1.x), f31 = B1 * cospix(c1.y);

#pragma unroll
            for (int o = 0; o < NOUT; ++o) {
                const float4 w = *(const float4*)(fc_w + o * NPIX + 4 * p);
                acc0[o] += A0 * w.x + B0 * w.y + f20 * w.z + f30 * w.w;
                acc1[o] += A1 * w.x + B1 * w.y + f21 * w.z + f31 * w.w;
            }
        }
    }

    // butterfly reduce -> every lane has the totals for both images
#pragma unroll
    for (int o = 0; o < NOUT; ++o) {
#pragma unroll
        for (int off = 32; off > 0; off >>= 1) {
            acc0[o] += __shfl_xor(acc0[o], off, 64);
            acc1[o] += __shfl_xor(acc1[o], off, 64);
        }
    }

    // lane 0 -> image b0, lane 1 -> image b0+1 (parallel softmax tails)
    if (lane < 2) {
        const int b = b0 + lane;
        float lg[NOUT];
        float m = -1e30f;
#pragma unroll
        for (int o = 0; o < NOUT; ++o) {
            const float a = (lane == 0) ? acc0[o] : acc1[o];
            lg[o] = a + fc_b[o];
            m = fmaxf(m, lg[o]);
        }
        float sum = 0.0f;
#pragma unroll
        for (int o = 0; o < NOUT; ++o) sum += expf(lg[o] - m);
        const float lse = m + logf(sum);
        float* ob = out + (size_t)b * NOUT;
#pragma unroll
        for (int o = 0; o < NOUT; ++o) ob[o] = lg[o] - lse;
    }
}

extern "C" void kernel_launch(void* const* d_in, const int* in_sizes, int n_in,
                              void* d_out, int out_size, void* d_ws, size_t ws_size,
                              hipStream_t stream) {
    const int*   x      = (const int*)d_in[0];
    // d_in[1] = params — provably cannot affect the output (unit-modulus
    // diagonal phases + basis-permutation CNOTs leave |amp|^2 invariant).
    const float* fc_w   = (const float*)d_in[2];
    const float* fc_b   = (const float*)d_in[3];
    float* out = (float*)d_out;
    const int B = in_sizes[0] / NPIX;  // 4096
    const int grid = (B + WPB * IPW - 1) / (WPB * IPW);  // 512
    quanv_analytic3_kernel<<<grid, BD, 0, stream>>>(x, fc_w, fc_b, out, B);
}